// Round 1
// baseline (240.164 us; speedup 1.0000x reference)
//
#include <hip/hip_runtime.h>
#include <math.h>

static __device__ __forceinline__ float leaky(float v) {
    return fmaxf(v, 0.2f * v);
}
static __device__ __forceinline__ float sigmoid_f(float z) {
    return __builtin_amdgcn_rcpf(1.0f + __expf(-z));
}

// Bilinear sample of 8 channels from LDS grid stored [y][x][c] (16B-aligned rows of 8 floats).
static __device__ __forceinline__ void sample8(const float* s_grid, float px, float py, float* f) {
    float ix = fmaf(px, 8.0f, 7.5f);   // ((x+1)*16-1)*0.5
    float iy = fmaf(py, 8.0f, 7.5f);
    float x0f = floorf(ix), y0f = floorf(iy);
    float wx1 = ix - x0f, wy1 = iy - y0f;
    float wx0 = 1.0f - wx1, wy0 = 1.0f - wy1;
    int x0 = (int)x0f, y0 = (int)y0f;
    int x1 = x0 + 1, y1 = y0 + 1;
    float vx0 = (x0 >= 0 && x0 < 16) ? 1.0f : 0.0f;
    float vx1 = (x1 >= 0 && x1 < 16) ? 1.0f : 0.0f;
    float vy0 = (y0 >= 0 && y0 < 16) ? 1.0f : 0.0f;
    float vy1 = (y1 >= 0 && y1 < 16) ? 1.0f : 0.0f;
    int xc0 = min(max(x0, 0), 15), xc1 = min(max(x1, 0), 15);
    int yc0 = min(max(y0, 0), 15), yc1 = min(max(y1, 0), 15);
    float w00 = (wy0 * vy0) * (wx0 * vx0);
    float w01 = (wy0 * vy0) * (wx1 * vx1);
    float w10 = (wy1 * vy1) * (wx0 * vx0);
    float w11 = (wy1 * vy1) * (wx1 * vx1);
    const float4* G = reinterpret_cast<const float4*>(s_grid);
    int i00 = (yc0 * 16 + xc0) * 2, i01 = (yc0 * 16 + xc1) * 2;
    int i10 = (yc1 * 16 + xc0) * 2, i11 = (yc1 * 16 + xc1) * 2;
    float4 a0 = G[i00], a1 = G[i00 + 1];
    float4 b0 = G[i01], b1 = G[i01 + 1];
    float4 c0 = G[i10], c1 = G[i10 + 1];
    float4 d0 = G[i11], d1 = G[i11 + 1];
    f[0] = w00 * a0.x + w01 * b0.x + w10 * c0.x + w11 * d0.x;
    f[1] = w00 * a0.y + w01 * b0.y + w10 * c0.y + w11 * d0.y;
    f[2] = w00 * a0.z + w01 * b0.z + w10 * c0.z + w11 * d0.z;
    f[3] = w00 * a0.w + w01 * b0.w + w10 * c0.w + w11 * d0.w;
    f[4] = w00 * a1.x + w01 * b1.x + w10 * c1.x + w11 * d1.x;
    f[5] = w00 * a1.y + w01 * b1.y + w10 * c1.y + w11 * d1.y;
    f[6] = w00 * a1.z + w01 * b1.z + w10 * c1.z + w11 * d1.z;
    f[7] = w00 * a1.w + w01 * b1.w + w10 * c1.w + w11 * d1.w;
}

__global__ __launch_bounds__(256) void tinymlp_fused(
    const float* __restrict__ xin, const float* __restrict__ grid,
    const float* __restrict__ W1, const float* __restrict__ b1,
    const float* __restrict__ W2, const float* __restrict__ b2,
    const float* __restrict__ W3, const float* __restrict__ b3,
    float* __restrict__ out, long long npix)
{
    __shared__ __align__(16) float s_grid[2048];   // [y][x][c] 16*16*8
    __shared__ __align__(16) float s_W1[128];      // [16][8]
    __shared__ __align__(16) float s_W2[256];      // [16][16]
    __shared__ __align__(16) float s_W3[48];       // [3][16]
    __shared__ __align__(16) float s_b1[16];
    __shared__ __align__(16) float s_b2[16];
    __shared__ __align__(16) float s_b3[4];

    const int tid = threadIdx.x;
    // grid[c][cell] -> s_grid[cell*8+c]; contiguous LDS writes, scattered (L2-hit) global reads
    #pragma unroll
    for (int k = 0; k < 8; ++k) {
        int i = tid + k * 256;
        s_grid[i] = grid[(i & 7) * 256 + (i >> 3)];
    }
    if (tid < 128) s_W1[tid] = W1[tid];
    if (tid >= 128 && tid < 144) s_b1[tid - 128] = b1[tid - 128];
    if (tid >= 144 && tid < 160) s_b2[tid - 144] = b2[tid - 144];
    if (tid >= 160 && tid < 208) s_W3[tid - 160] = W3[tid - 160];
    if (tid >= 208 && tid < 211) s_b3[tid - 208] = b3[tid - 208];
    s_W2[tid] = W2[tid];
    __syncthreads();

    const long long q = (long long)blockIdx.x * 256 + tid;
    const long long pix0 = q * 4;
    if (pix0 >= npix) return;

    if (pix0 + 4 <= npix) {
        // ---- fast path: 4 pixels per thread, weight LDS broadcasts amortized 4x ----
        float4 cA = *reinterpret_cast<const float4*>(xin + pix0 * 2);
        float4 cB = *reinterpret_cast<const float4*>(xin + pix0 * 2 + 4);
        float PX[4] = {cA.x, cA.z, cB.x, cB.z};
        float PY[4] = {cA.y, cA.w, cB.y, cB.w};

        float feat[4][8];
        #pragma unroll
        for (int p = 0; p < 4; ++p) sample8(s_grid, PX[p], PY[p], feat[p]);

        float h1[4][16];
        #pragma unroll
        for (int o = 0; o < 16; ++o) {
            const float4 wA = *reinterpret_cast<const float4*>(&s_W1[o * 8]);
            const float4 wB = *reinterpret_cast<const float4*>(&s_W1[o * 8 + 4]);
            const float bb = s_b1[o];
            #pragma unroll
            for (int p = 0; p < 4; ++p) {
                float a = bb;
                a = fmaf(wA.x, feat[p][0], a);
                a = fmaf(wA.y, feat[p][1], a);
                a = fmaf(wA.z, feat[p][2], a);
                a = fmaf(wA.w, feat[p][3], a);
                a = fmaf(wB.x, feat[p][4], a);
                a = fmaf(wB.y, feat[p][5], a);
                a = fmaf(wB.z, feat[p][6], a);
                a = fmaf(wB.w, feat[p][7], a);
                h1[p][o] = leaky(a);
            }
        }

        float h2[4][16];
        #pragma unroll
        for (int o = 0; o < 16; ++o) {
            const float bb = s_b2[o];
            float a0 = bb, a1 = bb, a2 = bb, a3 = bb;
            #pragma unroll
            for (int c4 = 0; c4 < 4; ++c4) {
                const float4 w = *reinterpret_cast<const float4*>(&s_W2[o * 16 + c4 * 4]);
                a0 = fmaf(w.x, h1[0][c4*4+0], a0); a0 = fmaf(w.y, h1[0][c4*4+1], a0);
                a0 = fmaf(w.z, h1[0][c4*4+2], a0); a0 = fmaf(w.w, h1[0][c4*4+3], a0);
                a1 = fmaf(w.x, h1[1][c4*4+0], a1); a1 = fmaf(w.y, h1[1][c4*4+1], a1);
                a1 = fmaf(w.z, h1[1][c4*4+2], a1); a1 = fmaf(w.w, h1[1][c4*4+3], a1);
                a2 = fmaf(w.x, h1[2][c4*4+0], a2); a2 = fmaf(w.y, h1[2][c4*4+1], a2);
                a2 = fmaf(w.z, h1[2][c4*4+2], a2); a2 = fmaf(w.w, h1[2][c4*4+3], a2);
                a3 = fmaf(w.x, h1[3][c4*4+0], a3); a3 = fmaf(w.y, h1[3][c4*4+1], a3);
                a3 = fmaf(w.z, h1[3][c4*4+2], a3); a3 = fmaf(w.w, h1[3][c4*4+3], a3);
            }
            h2[0][o] = leaky(a0); h2[1][o] = leaky(a1);
            h2[2][o] = leaky(a2); h2[3][o] = leaky(a3);
        }

        float y[4][3];
        #pragma unroll
        for (int o = 0; o < 3; ++o) {
            const float bb = s_b3[o];
            float a0 = bb, a1 = bb, a2 = bb, a3 = bb;
            #pragma unroll
            for (int c4 = 0; c4 < 4; ++c4) {
                const float4 w = *reinterpret_cast<const float4*>(&s_W3[o * 16 + c4 * 4]);
                a0 = fmaf(w.x, h2[0][c4*4+0], a0); a0 = fmaf(w.y, h2[0][c4*4+1], a0);
                a0 = fmaf(w.z, h2[0][c4*4+2], a0); a0 = fmaf(w.w, h2[0][c4*4+3], a0);
                a1 = fmaf(w.x, h2[1][c4*4+0], a1); a1 = fmaf(w.y, h2[1][c4*4+1], a1);
                a1 = fmaf(w.z, h2[1][c4*4+2], a1); a1 = fmaf(w.w, h2[1][c4*4+3], a1);
                a2 = fmaf(w.x, h2[2][c4*4+0], a2); a2 = fmaf(w.y, h2[2][c4*4+1], a2);
                a2 = fmaf(w.z, h2[2][c4*4+2], a2); a2 = fmaf(w.w, h2[2][c4*4+3], a2);
                a3 = fmaf(w.x, h2[3][c4*4+0], a3); a3 = fmaf(w.y, h2[3][c4*4+1], a3);
                a3 = fmaf(w.z, h2[3][c4*4+2], a3); a3 = fmaf(w.w, h2[3][c4*4+3], a3);
            }
            y[0][o] = sigmoid_f(a0); y[1][o] = sigmoid_f(a1);
            y[2][o] = sigmoid_f(a2); y[3][o] = sigmoid_f(a3);
        }

        float4* op = reinterpret_cast<float4*>(out + pix0 * 3);
        op[0] = make_float4(y[0][0], y[0][1], y[0][2], y[1][0]);
        op[1] = make_float4(y[1][1], y[1][2], y[2][0], y[2][1]);
        op[2] = make_float4(y[2][2], y[3][0], y[3][1], y[3][2]);
    } else {
        // ---- tail: per-pixel scalar path ----
        for (long long pp = pix0; pp < npix; ++pp) {
            float px = xin[pp * 2], py = xin[pp * 2 + 1];
            float f[8];
            sample8(s_grid, px, py, f);
            float hh1[16], hh2[16];
            #pragma unroll
            for (int o = 0; o < 16; ++o) {
                float a = s_b1[o];
                #pragma unroll
                for (int c = 0; c < 8; ++c) a = fmaf(s_W1[o * 8 + c], f[c], a);
                hh1[o] = leaky(a);
            }
            #pragma unroll
            for (int o = 0; o < 16; ++o) {
                float a = s_b2[o];
                #pragma unroll
                for (int c = 0; c < 16; ++c) a = fmaf(s_W2[o * 16 + c], hh1[c], a);
                hh2[o] = leaky(a);
            }
            #pragma unroll
            for (int o = 0; o < 3; ++o) {
                float a = s_b3[o];
                #pragma unroll
                for (int c = 0; c < 16; ++c) a = fmaf(s_W3[o * 16 + c], hh2[c], a);
                out[pp * 3 + o] = sigmoid_f(a);
            }
        }
    }
}

extern "C" void kernel_launch(void* const* d_in, const int* in_sizes, int n_in,
                              void* d_out, int out_size, void* d_ws, size_t ws_size,
                              hipStream_t stream)
{
    const float* xin  = (const float*)d_in[0];
    const float* grid = (const float*)d_in[1];
    const float* W1   = (const float*)d_in[2];
    const float* b1   = (const float*)d_in[3];
    const float* W2   = (const float*)d_in[4];
    const float* b2   = (const float*)d_in[5];
    const float* W3   = (const float*)d_in[6];
    const float* b3   = (const float*)d_in[7];
    float* out = (float*)d_out;

    long long npix = (long long)in_sizes[0] / 2;           // 8*1024*1024
    long long nq = (npix + 3) / 4;                         // quads
    int nblocks = (int)((nq + 255) / 256);
    tinymlp_fused<<<nblocks, 256, 0, stream>>>(xin, grid, W1, b1, W2, b2, W3, b3, out, npix);
}

// Round 2
// 164.590 us; speedup vs baseline: 1.4592x; 1.4592x over previous
//
#include <hip/hip_runtime.h>
#include <math.h>

#define NCELL   324   // 18x18 grid with zero border (no clamp/validity needed for coords in [-1,1])
#define CSTRIDE 20    // floats per cell in LDS: 5 float4 chunks; 5*cell+j mod 8 spreads all bank groups

static __device__ __forceinline__ float leaky(float v) { return fmaxf(v, 0.2f * v); }
static __device__ __forceinline__ float sigmoid_f(float z) {
    return __builtin_amdgcn_rcpf(1.0f + __expf(-z));
}

// G1[cell][o] = sum_c W1[o][c] * grid[c][cell], on an 18x18 zero-padded grid.
__global__ __launch_bounds__(64) void fuse_grid_k(const float* __restrict__ grid,
                                                  const float* __restrict__ W1,
                                                  float* __restrict__ G1) {
    int cell = blockIdx.x * 64 + threadIdx.x;
    if (cell >= NCELL) return;
    int yy = (cell * 3641) >> 16;   // cell / 18
    int xx = cell - yy * 18;
    float o16[16];
    if (yy == 0 || yy == 17 || xx == 0 || xx == 17) {
        #pragma unroll
        for (int o = 0; o < 16; ++o) o16[o] = 0.f;
    } else {
        float g[8];
        int base = (yy - 1) * 16 + (xx - 1);
        #pragma unroll
        for (int c = 0; c < 8; ++c) g[c] = grid[c * 256 + base];
        #pragma unroll
        for (int o = 0; o < 16; ++o) {
            float a = 0.f;
            #pragma unroll
            for (int c = 0; c < 8; ++c) a = fmaf(W1[o * 8 + c], g[c], a);
            o16[o] = a;
        }
    }
    #pragma unroll
    for (int o = 0; o < 16; ++o) G1[cell * 16 + o] = o16[o];
}

__global__ __launch_bounds__(256, 4) void tinymlp_main(
    const float* __restrict__ xin,
    const float* __restrict__ G1,     // 324*16 fused grid in d_ws (if useWs)
    const float* __restrict__ grid,   // fallback path only
    const float* __restrict__ W1,
    const float* __restrict__ b1,
    const float* __restrict__ W2, const float* __restrict__ b2,
    const float* __restrict__ W3, const float* __restrict__ b3,
    float* __restrict__ out, long long npix, int useWs)
{
    __shared__ __align__(16) float s_G1[NCELL * CSTRIDE];   // 25,920 B — only LDS use
    const int tid = threadIdx.x;

    if (useWs) {
        // stage compact [cell][16] -> strided [cell][20]; 1296 float4 chunks
        const float4* src = reinterpret_cast<const float4*>(G1);
        #pragma unroll
        for (int k = 0; k < 6; ++k) {
            int c = tid + k * 256;
            if (c < NCELL * 4) {
                int cell = c >> 2, j = c & 3;
                *reinterpret_cast<float4*>(&s_G1[cell * CSTRIDE + j * 4]) = src[c];
            }
        }
    } else {
        // fallback: compute G1 in-block (only if ws too small)
        for (int cell = tid; cell < NCELL; cell += 256) {
            int yy = (cell * 3641) >> 16;
            int xx = cell - yy * 18;
            bool border = (yy == 0) | (yy == 17) | (xx == 0) | (xx == 17);
            int base = border ? 0 : ((yy - 1) * 16 + (xx - 1));
            float g[8];
            #pragma unroll
            for (int c = 0; c < 8; ++c) g[c] = grid[c * 256 + base];
            float m = border ? 0.f : 1.f;
            #pragma unroll
            for (int o = 0; o < 16; ++o) {
                float a = 0.f;
                #pragma unroll
                for (int cc = 0; cc < 8; ++cc) a = fmaf(W1[o * 8 + cc], g[cc], a);
                s_G1[cell * CSTRIDE + o] = a * m;
            }
        }
    }
    __syncthreads();

    const long long q = (long long)blockIdx.x * 256 + tid;
    const long long pix0 = q * 2;
    if (pix0 >= npix) return;
    const bool two = (pix0 + 1) < npix;

    float4 cc;
    if (two) {
        cc = *reinterpret_cast<const float4*>(xin + pix0 * 2);
    } else {
        float2 t = *reinterpret_cast<const float2*>(xin + pix0 * 2);
        cc = make_float4(t.x, t.y, t.x, t.y);
    }

    // ---- fused sample + layer1 (pre-activation = bilinear(G1) + b1) ----
    float h1[2][16];
    #pragma unroll
    for (int p = 0; p < 2; ++p) {
        float px = p ? cc.z : cc.x;
        float py = p ? cc.w : cc.y;
        float ix = fmaf(px, 8.0f, 8.5f);   // ((x+1)*16-1)*0.5 shifted +1 for border
        float iy = fmaf(py, 8.0f, 8.5f);
        float x0f = floorf(ix), y0f = floorf(iy);
        float wx1 = ix - x0f, wy1 = iy - y0f;
        float wx0 = 1.0f - wx1, wy0 = 1.0f - wy1;
        int x0 = (int)x0f, y0 = (int)y0f;
        float w00 = wy0 * wx0, w01 = wy0 * wx1, w10 = wy1 * wx0, w11 = wy1 * wx1;
        const float* p00 = s_G1 + (y0 * 18 + x0) * CSTRIDE;
        const float* p10 = p00 + 18 * CSTRIDE;
        #pragma unroll
        for (int j = 0; j < 4; ++j) {
            float4 A = *reinterpret_cast<const float4*>(p00 + 4 * j);
            float4 B = *reinterpret_cast<const float4*>(p00 + CSTRIDE + 4 * j);
            float4 C = *reinterpret_cast<const float4*>(p10 + 4 * j);
            float4 D = *reinterpret_cast<const float4*>(p10 + CSTRIDE + 4 * j);
            float v0 = fmaf(w00, A.x, b1[4 * j + 0]);   // b1: uniform -> s_load
            float v1 = fmaf(w00, A.y, b1[4 * j + 1]);
            float v2 = fmaf(w00, A.z, b1[4 * j + 2]);
            float v3 = fmaf(w00, A.w, b1[4 * j + 3]);
            v0 = fmaf(w01, B.x, v0); v1 = fmaf(w01, B.y, v1);
            v2 = fmaf(w01, B.z, v2); v3 = fmaf(w01, B.w, v3);
            v0 = fmaf(w10, C.x, v0); v1 = fmaf(w10, C.y, v1);
            v2 = fmaf(w10, C.z, v2); v3 = fmaf(w10, C.w, v3);
            v0 = fmaf(w11, D.x, v0); v1 = fmaf(w11, D.y, v1);
            v2 = fmaf(w11, D.z, v2); v3 = fmaf(w11, D.w, v3);
            h1[p][4 * j + 0] = leaky(v0); h1[p][4 * j + 1] = leaky(v1);
            h1[p][4 * j + 2] = leaky(v2); h1[p][4 * j + 3] = leaky(v3);
        }
    }

    // ---- layer 2: weights via scalar loads (uniform, s_load through sK$) ----
    float h2[2][16];
    #pragma unroll
    for (int o = 0; o < 16; ++o) {
        float a0 = b2[o], a1 = b2[o];
        #pragma unroll
        for (int c = 0; c < 16; ++c) {
            float w = W2[o * 16 + c];
            a0 = fmaf(w, h1[0][c], a0);
            a1 = fmaf(w, h1[1][c], a1);
        }
        h2[0][o] = leaky(a0);
        h2[1][o] = leaky(a1);
    }

    // ---- layer 3 + sigmoid ----
    float y[2][3];
    #pragma unroll
    for (int o = 0; o < 3; ++o) {
        float a0 = b3[o], a1 = b3[o];
        #pragma unroll
        for (int c = 0; c < 16; ++c) {
            float w = W3[o * 16 + c];
            a0 = fmaf(w, h2[0][c], a0);
            a1 = fmaf(w, h2[1][c], a1);
        }
        y[0][o] = sigmoid_f(a0);
        y[1][o] = sigmoid_f(a1);
    }

    float* po = out + pix0 * 3;
    if (two) {
        float2* op = reinterpret_cast<float2*>(po);
        op[0] = make_float2(y[0][0], y[0][1]);
        op[1] = make_float2(y[0][2], y[1][0]);
        op[2] = make_float2(y[1][1], y[1][2]);
    } else {
        po[0] = y[0][0]; po[1] = y[0][1]; po[2] = y[0][2];
    }
}

extern "C" void kernel_launch(void* const* d_in, const int* in_sizes, int n_in,
                              void* d_out, int out_size, void* d_ws, size_t ws_size,
                              hipStream_t stream)
{
    const float* xin  = (const float*)d_in[0];
    const float* grid = (const float*)d_in[1];
    const float* W1   = (const float*)d_in[2];
    const float* b1   = (const float*)d_in[3];
    const float* W2   = (const float*)d_in[4];
    const float* b2   = (const float*)d_in[5];
    const float* W3   = (const float*)d_in[6];
    const float* b3   = (const float*)d_in[7];
    float* out = (float*)d_out;

    long long npix = (long long)in_sizes[0] / 2;
    int useWs = (ws_size >= (size_t)(NCELL * 16 * 4)) ? 1 : 0;
    float* g1 = (float*)d_ws;

    if (useWs) {
        fuse_grid_k<<<(NCELL + 63) / 64, 64, 0, stream>>>(grid, W1, g1);
    }
    long long nth = (npix + 1) / 2;
    int nblocks = (int)((nth + 255) / 256);
    tinymlp_main<<<nblocks, 256, 0, stream>>>(xin, g1, grid, W1, b1, W2, b2, W3, b3,
                                              out, npix, useWs);
}

// Round 4
// 85.408 us; speedup vs baseline: 2.8119x; 1.9271x over previous
//
#include <hip/hip_runtime.h>
#include <hip/hip_fp16.h>
#include <math.h>

typedef _Float16 half8_t __attribute__((ext_vector_type(8)));
typedef _Float16 h2_t    __attribute__((ext_vector_type(2)));
typedef float    f32x4_t __attribute__((ext_vector_type(4)));

#define NCELL 324            // 18x18 zero-border grid
#define CST   24             // f16 per cell row (48 B, 16B-aligned, bank-spread)
#define G1H   (NCELL * CST)  // 7776 f16 = 15552 B

static __device__ __forceinline__ float sigmoid_f(float z) {
    return __builtin_amdgcn_rcpf(1.0f + __expf(-z));
}
static __device__ __forceinline__ h2_t bc_h2(int v) { return __builtin_bit_cast(h2_t, v); }
static __device__ __forceinline__ int  bc_i(h2_t v) { return __builtin_bit_cast(int, v); }

static __device__ __forceinline__ h2_t pk_max(h2_t a, h2_t b) {
#if __has_builtin(__builtin_elementwise_max)
    return __builtin_elementwise_max(a, b);
#else
    h2_t r;
    r[0] = a[0] > b[0] ? a[0] : b[0];
    r[1] = a[1] > b[1] ? a[1] : b[1];
    return r;
#endif
}
static __device__ __forceinline__ f32x4_t leaky4(f32x4_t a) {
#if __has_builtin(__builtin_elementwise_max)
    return __builtin_elementwise_max(a, a * 0.2f);
#else
    f32x4_t r;
    #pragma unroll
    for (int i = 0; i < 4; ++i) r[i] = fmaxf(a[i], 0.2f * a[i]);
    return r;
#endif
}

// G1[cell][o] = sum_c W1[o][c]*grid[c][cell] + b1[o]  (border cells = b1: bilinear
// weights sum to 1, so bilinear(G1') == bilinear(W1·g) + b1 exactly). f16, 24-stride.
__global__ __launch_bounds__(64) void fuse_grid_k(const float* __restrict__ grid,
                                                  const float* __restrict__ W1,
                                                  const float* __restrict__ b1,
                                                  __half* __restrict__ G1) {
    int cell = blockIdx.x * 64 + threadIdx.x;
    if (cell >= NCELL) return;
    int yy = (cell * 3641) >> 16;          // /18
    int xx = cell - yy * 18;
    bool border = (yy == 0) | (yy == 17) | (xx == 0) | (xx == 17);
    int base = border ? 0 : ((yy - 1) * 16 + (xx - 1));
    float g[8];
    #pragma unroll
    for (int c = 0; c < 8; ++c) g[c] = grid[c * 256 + base];
    float m = border ? 0.f : 1.f;
    __align__(16) __half tmp[24];
    #pragma unroll
    for (int o = 0; o < 16; ++o) {
        float a = 0.f;
        #pragma unroll
        for (int c = 0; c < 8; ++c) a = fmaf(W1[o * 8 + c], g[c], a);
        tmp[o] = __float2half(fmaf(a, m, b1[o]));
    }
    #pragma unroll
    for (int o = 16; o < 24; ++o) tmp[o] = __float2half(0.f);
    int4* dst = reinterpret_cast<int4*>(G1 + cell * CST);
    const int4* src = reinterpret_cast<const int4*>(tmp);
    dst[0] = src[0]; dst[1] = src[1]; dst[2] = src[2];
}

__global__ __launch_bounds__(512) void mlp_main(
    const float* __restrict__ xin, const __half* __restrict__ G1,
    const float* __restrict__ W2, const float* __restrict__ b2,
    const float* __restrict__ W3, const float* __restrict__ b3,
    float* __restrict__ out, long long npix)
{
    __shared__ __align__(16) _Float16 sG[G1H];        // 15552 B
    __shared__ __align__(16) _Float16 sS[8][1536];    // 3 KB per-wave scratch

    const int tid  = threadIdx.x;
    const int lane = tid & 63;
    const int wv   = tid >> 6;
    const int qg   = lane >> 4;      // 0..3 lane group
    const int nn   = lane & 15;

    // ---- stage fused grid into LDS (972 b128 chunks) ----
    {
        const int4* src = reinterpret_cast<const int4*>(G1);
        int4* dst = reinterpret_cast<int4*>(sG);
        #pragma unroll
        for (int k = 0; k < 2; ++k) {
            int i = tid + k * 512;
            if (i < G1H / 8) dst[i] = src[i];
        }
    }

    // ---- per-lane constant MFMA fragments (A: k = 8*(lane/16)+j; groups 2,3 = 0) ----
    half8_t A2, A3;
    if (qg < 2) {
        const float4 u0 = *reinterpret_cast<const float4*>(W2 + nn * 16 + qg * 8);
        const float4 u1 = *reinterpret_cast<const float4*>(W2 + nn * 16 + qg * 8 + 4);
        A2[0] = (_Float16)u0.x; A2[1] = (_Float16)u0.y; A2[2] = (_Float16)u0.z; A2[3] = (_Float16)u0.w;
        A2[4] = (_Float16)u1.x; A2[5] = (_Float16)u1.y; A2[6] = (_Float16)u1.z; A2[7] = (_Float16)u1.w;
    } else {
        #pragma unroll
        for (int j = 0; j < 8; ++j) A2[j] = (_Float16)0.f;
    }
    if (qg < 2 && nn < 3) {
        const float4 u0 = *reinterpret_cast<const float4*>(W3 + nn * 16 + qg * 8);
        const float4 u1 = *reinterpret_cast<const float4*>(W3 + nn * 16 + qg * 8 + 4);
        A3[0] = (_Float16)u0.x; A3[1] = (_Float16)u0.y; A3[2] = (_Float16)u0.z; A3[3] = (_Float16)u0.w;
        A3[4] = (_Float16)u1.x; A3[5] = (_Float16)u1.y; A3[6] = (_Float16)u1.z; A3[7] = (_Float16)u1.w;
    } else {
        #pragma unroll
        for (int j = 0; j < 8; ++j) A3[j] = (_Float16)0.f;
    }
    f32x4_t b2v;   // bias as MFMA C-in: row = 4*qg + r
    {
        float4 t = *reinterpret_cast<const float4*>(b2 + qg * 4);
        b2v[0] = t.x; b2v[1] = t.y; b2v[2] = t.z; b2v[3] = t.w;
    }
    f32x4_t b3v;
    b3v[0] = b3[0]; b3v[1] = b3[1]; b3v[2] = b3[2]; b3v[3] = 0.f;

    __syncthreads();

    const long long px = (long long)blockIdx.x * 512 + tid;
    const bool live = px < npix;
    float2 cc = live ? *reinterpret_cast<const float2*>(xin + 2 * px) : make_float2(0.f, 0.f);

    // ---- coords -> cell + bilinear weights (f16 packed) ----
    float ix = fmaf(cc.x, 8.f, 8.5f);   // +1 cell shift for zero border
    float iy = fmaf(cc.y, 8.f, 8.5f);
    float xf = floorf(ix), yf = floorf(iy);
    float wx1 = ix - xf, wy1 = iy - yf;
    float wx0 = 1.f - wx1, wy0 = 1.f - wy1;
    int x0 = (int)xf, y0 = (int)yf;     // in [0,16] for coords in [-1,1]
    const float w00f = wy0 * wx0, w01f = wy0 * wx1, w10f = wy1 * wx0, w11f = wy1 * wx1;
    const h2_t W00 = { (_Float16)w00f, (_Float16)w00f };
    const h2_t W01 = { (_Float16)w01f, (_Float16)w01f };
    const h2_t W10 = { (_Float16)w10f, (_Float16)w10f };
    const h2_t W11 = { (_Float16)w11f, (_Float16)w11f };
    const h2_t K02 = { (_Float16)0.2f, (_Float16)0.2f };

    // ---- gather 4 corners (8x ds_read_b128, imm offsets) ----
    const _Float16* gp = sG + (y0 * 18 + x0) * CST;
    const int4 cA0 = *reinterpret_cast<const int4*>(gp);
    const int4 cA1 = *reinterpret_cast<const int4*>(gp + 8);
    const int4 cB0 = *reinterpret_cast<const int4*>(gp + CST);
    const int4 cB1 = *reinterpret_cast<const int4*>(gp + CST + 8);
    const int4 cC0 = *reinterpret_cast<const int4*>(gp + 18 * CST);
    const int4 cC1 = *reinterpret_cast<const int4*>(gp + 18 * CST + 8);
    const int4 cD0 = *reinterpret_cast<const int4*>(gp + 19 * CST);
    const int4 cD1 = *reinterpret_cast<const int4*>(gp + 19 * CST + 8);

    // ---- fused bilinear + b1 + leaky, packed f16 (v_pk_fma_f16 / v_pk_max_f16) ----
    auto bl = [&](int a, int b, int c, int d) -> int {
        h2_t v = bc_h2(a) * W00;
        v = bc_h2(b) * W01 + v;
        v = bc_h2(c) * W10 + v;
        v = bc_h2(d) * W11 + v;
        return bc_i(pk_max(v, v * K02));   // leaky 0.2
    };
    int4 w0, w1;
    w0.x = bl(cA0.x, cB0.x, cC0.x, cD0.x);
    w0.y = bl(cA0.y, cB0.y, cC0.y, cD0.y);
    w0.z = bl(cA0.z, cB0.z, cC0.z, cD0.z);
    w0.w = bl(cA0.w, cB0.w, cC0.w, cD0.w);
    w1.x = bl(cA1.x, cB1.x, cC1.x, cD1.x);
    w1.y = bl(cA1.y, cB1.y, cC1.y, cD1.y);
    w1.z = bl(cA1.z, cB1.z, cC1.z, cD1.z);
    w1.w = bl(cA1.w, cB1.w, cC1.w, cD1.w);

    // ---- h1 -> per-wave LDS [chblk 0/1][px][8ch] (conflict-free b128) ----
    _Float16* S = sS[wv];
    *reinterpret_cast<int4*>(S + lane * 8)       = w0;   // ch 0-7
    *reinterpret_cast<int4*>(S + 512 + lane * 8) = w1;   // ch 8-15

    // ---- B frags for layer 2: lane needs h1[k=8*qg+j][px=16g+nn]; groups 2,3 mirror 0,1 ----
    const _Float16* bp = S + (qg & 1) * 512 + nn * 8;
    half8_t f0 = *reinterpret_cast<const half8_t*>(bp);
    half8_t f1 = *reinterpret_cast<const half8_t*>(bp + 128);
    half8_t f2 = *reinterpret_cast<const half8_t*>(bp + 256);
    half8_t f3 = *reinterpret_cast<const half8_t*>(bp + 384);

    f32x4_t a0 = __builtin_amdgcn_mfma_f32_16x16x32_f16(A2, f0, b2v, 0, 0, 0);
    f32x4_t a1 = __builtin_amdgcn_mfma_f32_16x16x32_f16(A2, f1, b2v, 0, 0, 0);
    f32x4_t a2 = __builtin_amdgcn_mfma_f32_16x16x32_f16(A2, f2, b2v, 0, 0, 0);
    f32x4_t a3 = __builtin_amdgcn_mfma_f32_16x16x32_f16(A2, f3, b2v, 0, 0, 0);

    // ---- leaky (f32) + cvt f16, store h2 to LDS [px][24] (rows 48 B) ----
    auto h2st = [&](const f32x4_t& a_in, int g) {
        f32x4_t l = leaky4(a_in);
        h2_t d0 = { (_Float16)l[0], (_Float16)l[1] };
        h2_t d1 = { (_Float16)l[2], (_Float16)l[3] };
        int2 t; t.x = bc_i(d0); t.y = bc_i(d1);
        *reinterpret_cast<int2*>(S + (16 * g + nn) * 24 + qg * 4) = t;
    };
    h2st(a0, 0); h2st(a1, 1); h2st(a2, 2); h2st(a3, 3);

    // ---- B frags for layer 3 ----
    const _Float16* cp = S + nn * 24 + (qg & 1) * 8;
    half8_t e0 = *reinterpret_cast<const half8_t*>(cp);
    half8_t e1 = *reinterpret_cast<const half8_t*>(cp + 384);
    half8_t e2 = *reinterpret_cast<const half8_t*>(cp + 768);
    half8_t e3 = *reinterpret_cast<const half8_t*>(cp + 1152);

    f32x4_t y0v = __builtin_amdgcn_mfma_f32_16x16x32_f16(A3, e0, b3v, 0, 0, 0);
    f32x4_t y1v = __builtin_amdgcn_mfma_f32_16x16x32_f16(A3, e1, b3v, 0, 0, 0);
    f32x4_t y2v = __builtin_amdgcn_mfma_f32_16x16x32_f16(A3, e2, b3v, 0, 0, 0);
    f32x4_t y3v = __builtin_amdgcn_mfma_f32_16x16x32_f16(A3, e3, b3v, 0, 0, 0);

    // ---- redistribute y to all lanes (so sigmoid runs 64-wide), then store ----
    float* Yf = reinterpret_cast<float*>(S);   // h2 region dead after e-reads
    if (qg == 0) {                             // lanes 0-15 hold rows 0-2 (+junk row 3)
        *reinterpret_cast<f32x4_t*>(Yf + nn * 4)        = y0v;
        *reinterpret_cast<f32x4_t*>(Yf + (16 + nn) * 4) = y1v;
        *reinterpret_cast<f32x4_t*>(Yf + (32 + nn) * 4) = y2v;
        *reinterpret_cast<f32x4_t*>(Yf + (48 + nn) * 4) = y3v;
    }
    f32x4_t t4 = *reinterpret_cast<const f32x4_t*>(Yf + lane * 4);
    if (live) {
        float s0 = sigmoid_f(t4[0]);
        float s1 = sigmoid_f(t4[1]);
        float s2 = sigmoid_f(t4[2]);
        out[px * 3 + 0] = s0;
        out[px * 3 + 1] = s1;
        out[px * 3 + 2] = s2;
    }
}

extern "C" void kernel_launch(void* const* d_in, const int* in_sizes, int n_in,
                              void* d_out, int out_size, void* d_ws, size_t ws_size,
                              hipStream_t stream)
{
    const float* xin  = (const float*)d_in[0];
    const float* grid = (const float*)d_in[1];
    const float* W1   = (const float*)d_in[2];
    const float* b1   = (const float*)d_in[3];
    const float* W2   = (const float*)d_in[4];
    const float* b2   = (const float*)d_in[5];
    const float* W3   = (const float*)d_in[6];
    const float* b3   = (const float*)d_in[7];
    float* out = (float*)d_out;

    long long npix = (long long)in_sizes[0] / 2;
    __half* g1 = (__half*)d_ws;   // needs 15552 B

    fuse_grid_k<<<(NCELL + 63) / 64, 64, 0, stream>>>(grid, W1, b1, g1);
    int nb = (int)((npix + 511) / 512);
    mlp_main<<<nb, 512, 0, stream>>>(xin, g1, W2, b2, W3, b3, out, npix);
}

// Round 10
// 73.191 us; speedup vs baseline: 3.2813x; 1.1669x over previous
//
#include <hip/hip_runtime.h>
#include <hip/hip_fp16.h>
#include <math.h>

typedef _Float16 half8_t  __attribute__((ext_vector_type(8)));
typedef _Float16 h2_t     __attribute__((ext_vector_type(2)));
typedef float    f32x16_t __attribute__((ext_vector_type(16)));

#define NCELL 324            // 18x18 zero-border grid
#define CST   24             // f16 per cell row (48 B, 16B-aligned)
#define G1H   (NCELL * CST)  // 7776 f16 = 15552 B

static __device__ __forceinline__ float sigmoid_f(float z) {
    return __builtin_amdgcn_rcpf(1.0f + __expf(-z));
}
static __device__ __forceinline__ float leakyf(float v) { return fmaxf(v, 0.2f * v); }
static __device__ __forceinline__ h2_t bc_h2(int v) { return __builtin_bit_cast(h2_t, v); }
static __device__ __forceinline__ int  bc_i(h2_t v) { return __builtin_bit_cast(int, v); }

static __device__ __forceinline__ h2_t pk_max(h2_t a, h2_t b) {
#if __has_builtin(__builtin_elementwise_max)
    return __builtin_elementwise_max(a, b);
#else
    h2_t r; r[0] = a[0] > b[0] ? a[0] : b[0]; r[1] = a[1] > b[1] ? a[1] : b[1]; return r;
#endif
}
// pack two f32 -> 2x f16 with RNE (matches round-4's verified numerics)
static __device__ __forceinline__ int pk2rn(float a, float b) {
    h2_t t; t[0] = (_Float16)a; t[1] = (_Float16)b;
    return bc_i(t);
}

// G1[cell][o] = sum_c W1[o][c]*grid[c][cell] + b1[o]  (border cells = b1: bilinear
// weights sum to 1, so bilinear(G1') == bilinear(W1·g) + b1). f16, stride 24.
__global__ __launch_bounds__(64) void fuse_grid_k(const float* __restrict__ grid,
                                                  const float* __restrict__ W1,
                                                  const float* __restrict__ b1,
                                                  __half* __restrict__ G1) {
    int cell = blockIdx.x * 64 + threadIdx.x;
    if (cell >= NCELL) return;
    int yy = (cell * 3641) >> 16;          // /18
    int xx = cell - yy * 18;
    bool border = (yy == 0) | (yy == 17) | (xx == 0) | (xx == 17);
    int base = border ? 0 : ((yy - 1) * 16 + (xx - 1));
    float g[8];
    #pragma unroll
    for (int c = 0; c < 8; ++c) g[c] = grid[c * 256 + base];
    float m = border ? 0.f : 1.f;
    __align__(16) __half tmp[24];
    #pragma unroll
    for (int o = 0; o < 16; ++o) {
        float a = 0.f;
        #pragma unroll
        for (int c = 0; c < 8; ++c) a = fmaf(W1[o * 8 + c], g[c], a);
        tmp[o] = __float2half(fmaf(a, m, b1[o]));
    }
    #pragma unroll
    for (int o = 16; o < 24; ++o) tmp[o] = __float2half(0.f);
    int4* dst = reinterpret_cast<int4*>(G1 + cell * CST);
    const int4* src = reinterpret_cast<const int4*>(tmp);
    dst[0] = src[0]; dst[1] = src[1]; dst[2] = src[2];
}

__global__ __launch_bounds__(256, 4) void mlp_main(
    const float* __restrict__ xin, const __half* __restrict__ G1,
    const float* __restrict__ W2, const float* __restrict__ b2,
    const float* __restrict__ W3, const float* __restrict__ b3,
    float* __restrict__ out, long long npix)
{
    __shared__ __align__(16) _Float16 sG[G1H];       // 15552 B
    __shared__ __align__(16) _Float16 sS[4][1024];   // per-wave 2KB: [half 0/1][px][8ch]
    const int tid = threadIdx.x;

    {   // stage fused grid (972 int4 chunks)
        const int4* src = reinterpret_cast<const int4*>(G1);
        int4* dst = reinterpret_cast<int4*>(sG);
        #pragma unroll
        for (int k = 0; k < 4; ++k) {
            int i = tid + k * 256;
            if (i < G1H / 8) dst[i] = src[i];
        }
    }

    const int lane = tid & 63;
    const int hi   = lane >> 5;      // K-half selector
    const int r    = lane & 31;      // A-row / B-col
    const int wv   = tid >> 6;

    // ---- A-frags (32x32x16: row = lane&31, k = 8*hi + j) ----
    half8_t A2, A3;
    #pragma unroll
    for (int j = 0; j < 8; ++j) { A2[j] = (_Float16)0.f; A3[j] = (_Float16)0.f; }
    if (r < 16) {
        const float4 u0 = *reinterpret_cast<const float4*>(W2 + r * 16 + hi * 8);
        const float4 u1 = *reinterpret_cast<const float4*>(W2 + r * 16 + hi * 8 + 4);
        A2[0] = (_Float16)u0.x; A2[1] = (_Float16)u0.y; A2[2] = (_Float16)u0.z; A2[3] = (_Float16)u0.w;
        A2[4] = (_Float16)u1.x; A2[5] = (_Float16)u1.y; A2[6] = (_Float16)u1.z; A2[7] = (_Float16)u1.w;
    }
    if (r < 3) {
        const float4 u0 = *reinterpret_cast<const float4*>(W3 + r * 16 + hi * 8);
        const float4 u1 = *reinterpret_cast<const float4*>(W3 + r * 16 + hi * 8 + 4);
        A3[0] = (_Float16)u0.x; A3[1] = (_Float16)u0.y; A3[2] = (_Float16)u0.z; A3[3] = (_Float16)u0.w;
        A3[4] = (_Float16)u1.x; A3[5] = (_Float16)u1.y; A3[6] = (_Float16)u1.z; A3[7] = (_Float16)u1.w;
    }
    // ---- bias C-in (C/D row = (reg&3) + 8*(reg>>2) + 4*hi) ----
    f32x16_t b2v, b3v;
    #pragma unroll
    for (int j = 0; j < 16; ++j) { b2v[j] = 0.f; b3v[j] = 0.f; }
    {
        const float4 t0 = *reinterpret_cast<const float4*>(b2 + 4 * hi);
        const float4 t1 = *reinterpret_cast<const float4*>(b2 + 8 + 4 * hi);
        b2v[0] = t0.x; b2v[1] = t0.y; b2v[2] = t0.z; b2v[3] = t0.w;
        b2v[4] = t1.x; b2v[5] = t1.y; b2v[6] = t1.z; b2v[7] = t1.w;
    }
    if (hi == 0) { b3v[0] = b3[0]; b3v[1] = b3[1]; b3v[2] = b3[2]; }

    __syncthreads();

    _Float16* S = sS[wv];
    const h2_t K02 = { (_Float16)0.2f, (_Float16)0.2f };

    #pragma unroll
    for (int u = 0; u < 2; ++u) {
        const long long pxbase = (long long)blockIdx.x * 512 + wv * 128 + u * 64;
        const long long px = pxbase + lane;
        const bool live = px < npix;
        float2 cc = live ? *reinterpret_cast<const float2*>(xin + 2 * px)
                         : make_float2(0.f, 0.f);

        // ---- coords -> cell + bilinear weights ----
        float ix = fmaf(cc.x, 8.f, 8.5f);
        float iy = fmaf(cc.y, 8.f, 8.5f);
        float xf = floorf(ix), yf = floorf(iy);
        float wx1 = ix - xf, wy1 = iy - yf;
        float wx0 = 1.f - wx1, wy0 = 1.f - wy1;
        int cx0 = (int)xf, cy0 = (int)yf;
        float w00f = wy0 * wx0, w01f = wy0 * wx1, w10f = wy1 * wx0, w11f = wy1 * wx1;
        const h2_t W00 = { (_Float16)w00f, (_Float16)w00f };
        const h2_t W01 = { (_Float16)w01f, (_Float16)w01f };
        const h2_t W10 = { (_Float16)w10f, (_Float16)w10f };
        const h2_t W11 = { (_Float16)w11f, (_Float16)w11f };

        // ---- gather 4 corners (8x ds_read_b128) ----
        const _Float16* gp = sG + (cy0 * 18 + cx0) * CST;
        const int4 cA0 = *reinterpret_cast<const int4*>(gp);
        const int4 cA1 = *reinterpret_cast<const int4*>(gp + 8);
        const int4 cB0 = *reinterpret_cast<const int4*>(gp + CST);
        const int4 cB1 = *reinterpret_cast<const int4*>(gp + CST + 8);
        const int4 cC0 = *reinterpret_cast<const int4*>(gp + 18 * CST);
        const int4 cC1 = *reinterpret_cast<const int4*>(gp + 18 * CST + 8);
        const int4 cD0 = *reinterpret_cast<const int4*>(gp + 19 * CST);
        const int4 cD1 = *reinterpret_cast<const int4*>(gp + 19 * CST + 8);

        // ---- bilinear + leaky, packed f16 (b1 already folded into grid) ----
        auto bl = [&](int a, int b, int c, int d) -> int {
            h2_t v = bc_h2(a) * W00;
            v = bc_h2(b) * W01 + v;
            v = bc_h2(c) * W10 + v;
            v = bc_h2(d) * W11 + v;
            return bc_i(pk_max(v, v * K02));
        };
        int4 w0, w1;
        w0.x = bl(cA0.x, cB0.x, cC0.x, cD0.x);   // px=lane ch0-1
        w0.y = bl(cA0.y, cB0.y, cC0.y, cD0.y);
        w0.z = bl(cA0.z, cB0.z, cC0.z, cD0.z);
        w0.w = bl(cA0.w, cB0.w, cC0.w, cD0.w);
        w1.x = bl(cA1.x, cB1.x, cC1.x, cD1.x);   // px=lane ch8-9
        w1.y = bl(cA1.y, cB1.y, cC1.y, cD1.y);
        w1.z = bl(cA1.z, cB1.z, cC1.z, cD1.z);
        w1.w = bl(cA1.w, cB1.w, cC1.w, cD1.w);

        // ---- h1 -> per-wave LDS [half][px][8ch] (round-4-verified pattern) ----
        *reinterpret_cast<int4*>(S + lane * 8)       = w0;   // ch 0-7
        *reinterpret_cast<int4*>(S + 512 + lane * 8) = w1;   // ch 8-15

        // ---- layer-2 B-frags: lane (hi,r) <- h1[px][8*hi + j] ----
        half8_t fA = *reinterpret_cast<const half8_t*>(S + hi * 512 + r * 8);         // px 0-31
        half8_t fB = *reinterpret_cast<const half8_t*>(S + hi * 512 + (32 + r) * 8);  // px 32-63

        f32x16_t acc0 = __builtin_amdgcn_mfma_f32_32x32x16_f16(A2, fA, b2v, 0, 0, 0);
        f32x16_t acc1 = __builtin_amdgcn_mfma_f32_32x32x16_f16(A2, fB, b2v, 0, 0, 0);

        // ---- h2: leaky + f16, store to same [half][px][8ch] (DS pipe is in-order
        //      per wave, so these writes can't pass the fA/fB reads) ----
        // lane (hi,r) holds rows n=4hi..4hi+3 (regs 0-3) and n=8+4hi..+3 (regs 4-7).
        {
            int2 t0 = make_int2(pk2rn(leakyf(acc0[0]), leakyf(acc0[1])),
                                pk2rn(leakyf(acc0[2]), leakyf(acc0[3])));
            int2 t1 = make_int2(pk2rn(leakyf(acc0[4]), leakyf(acc0[5])),
                                pk2rn(leakyf(acc0[6]), leakyf(acc0[7])));
            *reinterpret_cast<int2*>(S + r * 8 + 4 * hi)       = t0;  // ch 4hi..4hi+3
            *reinterpret_cast<int2*>(S + 512 + r * 8 + 4 * hi) = t1;  // ch 8+4hi..
            int2 t2 = make_int2(pk2rn(leakyf(acc1[0]), leakyf(acc1[1])),
                                pk2rn(leakyf(acc1[2]), leakyf(acc1[3])));
            int2 t3 = make_int2(pk2rn(leakyf(acc1[4]), leakyf(acc1[5])),
                                pk2rn(leakyf(acc1[6]), leakyf(acc1[7])));
            *reinterpret_cast<int2*>(S + (32 + r) * 8 + 4 * hi)       = t2;
            *reinterpret_cast<int2*>(S + 512 + (32 + r) * 8 + 4 * hi) = t3;
        }

        // ---- layer-3 B-frags ----
        half8_t e0 = *reinterpret_cast<const half8_t*>(S + hi * 512 + r * 8);
        half8_t e1 = *reinterpret_cast<const half8_t*>(S + hi * 512 + (32 + r) * 8);

        f32x16_t yv0 = __builtin_amdgcn_mfma_f32_32x32x16_f16(A3, e0, b3v, 0, 0, 0);
        f32x16_t yv1 = __builtin_amdgcn_mfma_f32_32x32x16_f16(A3, e1, b3v, 0, 0, 0);

        // ---- output: lanes hi==0 hold rows 0-2 = (R,G,B) for px=r and px=32+r ----
        if (hi == 0) {
            long long p0 = pxbase + r;
            long long p1 = pxbase + 32 + r;
            if (p0 < npix) {
                float* po = out + p0 * 3;
                po[0] = sigmoid_f(yv0[0]);
                po[1] = sigmoid_f(yv0[1]);
                po[2] = sigmoid_f(yv0[2]);
            }
            if (p1 < npix) {
                float* po = out + p1 * 3;
                po[0] = sigmoid_f(yv1[0]);
                po[1] = sigmoid_f(yv1[1]);
                po[2] = sigmoid_f(yv1[2]);
            }
        }
    }
}

extern "C" void kernel_launch(void* const* d_in, const int* in_sizes, int n_in,
                              void* d_out, int out_size, void* d_ws, size_t ws_size,
                              hipStream_t stream)
{
    const float* xin  = (const float*)d_in[0];
    const float* grid = (const float*)d_in[1];
    const float* W1   = (const float*)d_in[2];
    const float* b1   = (const float*)d_in[3];
    const float* W2   = (const float*)d_in[4];
    const float* b2   = (const float*)d_in[5];
    const float* W3   = (const float*)d_in[6];
    const float* b3   = (const float*)d_in[7];
    float* out = (float*)d_out;

    long long npix = (long long)in_sizes[0] / 2;
    __half* g1 = (__half*)d_ws;   // 15552 B

    fuse_grid_k<<<(NCELL + 63) / 64, 64, 0, stream>>>(grid, W1, b1, g1);
    int nb = (int)((npix + 511) / 512);   // 256 threads x 2 px
    mlp_main<<<nb, 256, 0, stream>>>(xin, g1, W2, b2, W3, b3, out, npix);
}